// Round 1
// baseline (30915.189 us; speedup 1.0000x reference)
//
#include <hip/hip_runtime.h>
#include <hip/hip_fp16.h>

typedef unsigned int u32;
typedef unsigned short u16;

#define BB 64
#define TT 512
#define FF 128
#define HH 512
#define G4 2048  // 4*H

union UH2 { u32 u; __half2 h; };
__device__ inline __half2 u2h(u32 u) { UH2 t; t.u = u; return t.h; }

__device__ inline float sigm(float x) { return 1.0f / (1.0f + __expf(-x)); }
__device__ inline float tanh_fast(float x) { return 2.0f / (1.0f + __expf(-2.0f * x)) - 1.0f; }

// ---------------------------------------------------------------------------
// Pack Wh (f32 [512,2048]) -> f16 with k-pairs packed into dwords:
// P[k2*2048 + col] = (half(Wh[2k2,col]) , half(Wh[2k2+1,col]))
// Also zero the BN accumulators (re-poisoned to 0xAA before every launch).
// ---------------------------------------------------------------------------
__global__ __launch_bounds__(256) void pack_wh(
    const float* __restrict__ Wh1, const float* __restrict__ Wh2,
    u32* __restrict__ P1, u32* __restrict__ P2, float* __restrict__ accum)
{
    int idx = blockIdx.x * 256 + threadIdx.x;   // < 256*2048
    int k2 = idx >> 11, col = idx & 2047;
    {
        float a = Wh1[(2 * k2) * G4 + col];
        float b = Wh1[(2 * k2 + 1) * G4 + col];
        u16 ua = __half_as_ushort(__float2half(a));
        u16 ub = __half_as_ushort(__float2half(b));
        P1[idx] = (u32)ua | ((u32)ub << 16);
    }
    {
        float a = Wh2[(2 * k2) * G4 + col];
        float b = Wh2[(2 * k2 + 1) * G4 + col];
        u16 ua = __half_as_ushort(__float2half(a));
        u16 ub = __half_as_ushort(__float2half(b));
        P2[idx] = (u32)ua | ((u32)ub << 16);
    }
    if (idx < 2048) accum[idx] = 0.0f;
}

// ---------------------------------------------------------------------------
// Tiled fp32 GEMM: C(f16)[M,N] = A[M,K] @ B[K,N] + bias[N]
// A either f32 or f16; optional per-k affine on A (folded BatchNorm).
// BM=BN=64, BK=16, 256 threads, 4x4 per thread.
// ---------------------------------------------------------------------------
template <bool A_HALF, bool AFFINE>
__global__ __launch_bounds__(256) void gemm64(
    const void* __restrict__ Av, const float* __restrict__ B,
    const float* __restrict__ bias, const float* __restrict__ sc,
    const float* __restrict__ tr, __half* __restrict__ C,
    int M, int N, int K)
{
    __shared__ float sA[16][64];
    __shared__ float sB[16][64];
    const int tid = threadIdx.x;
    const int tx = tid & 15, ty = tid >> 4;
    const int bm = blockIdx.y << 6, bn = blockIdx.x << 6;
    const int lm = tid >> 2, lk = (tid & 3) << 2;
    const int br = tid >> 6, bc = tid & 63;
    float acc[4][4] = {};

    for (int k0 = 0; k0 < K; k0 += 16) {
        float av[4];
        if constexpr (A_HALF) {
            const __half* A = (const __half*)Av + (size_t)(bm + lm) * K + (k0 + lk);
            uint2 u = *(const uint2*)A;
            __half2 p0 = u2h(u.x), p1 = u2h(u.y);
            av[0] = __low2float(p0); av[1] = __high2float(p0);
            av[2] = __low2float(p1); av[3] = __high2float(p1);
        } else {
            const float4 v = *(const float4*)((const float*)Av + (size_t)(bm + lm) * K + (k0 + lk));
            av[0] = v.x; av[1] = v.y; av[2] = v.z; av[3] = v.w;
        }
        if constexpr (AFFINE) {
#pragma unroll
            for (int i = 0; i < 4; ++i) av[i] = av[i] * sc[k0 + lk + i] + tr[k0 + lk + i];
        }
#pragma unroll
        for (int i = 0; i < 4; ++i) sA[lk + i][lm] = av[i];
#pragma unroll
        for (int i = 0; i < 4; ++i)
            sB[br + 4 * i][bc] = B[(size_t)(k0 + br + 4 * i) * N + bn + bc];
        __syncthreads();
#pragma unroll
        for (int kk = 0; kk < 16; ++kk) {
            const float4 a4 = *(const float4*)&sA[kk][ty << 2];
            const float4 b4 = *(const float4*)&sB[kk][tx << 2];
            float aa[4] = {a4.x, a4.y, a4.z, a4.w};
            float bb[4] = {b4.x, b4.y, b4.z, b4.w};
#pragma unroll
            for (int i = 0; i < 4; ++i)
#pragma unroll
                for (int j = 0; j < 4; ++j) acc[i][j] += aa[i] * bb[j];
        }
        __syncthreads();
    }
#pragma unroll
    for (int i = 0; i < 4; ++i) {
        u16 q[4];
#pragma unroll
        for (int j = 0; j < 4; ++j) {
            float v = acc[i][j] + bias[bn + (tx << 2) + j];
            q[j] = __half_as_ushort(__float2half(v));
        }
        uint2 st;
        st.x = (u32)q[0] | ((u32)q[1] << 16);
        st.y = (u32)q[2] | ((u32)q[3] << 16);
        *(uint2*)(C + (size_t)(bm + (ty << 2) + i) * N + bn + (tx << 2)) = st;
    }
}

// ---------------------------------------------------------------------------
// LSTM scan: one block per batch row, 1024 threads.
// Thread owns gate columns (2*tid, 2*tid+1). h lives in LDS as f16 (packed
// as half2 over k-pairs). Inner dot uses __hfma2 (packed f16 FMA).
// Threads 0..511 then own hidden unit tid for the state update (c in reg).
// ---------------------------------------------------------------------------
__global__ __launch_bounds__(1024) void lstm_scan(
    const __half* __restrict__ xW,   // [B*T, 2048] f16 (x@Wx + b)
    const u32* __restrict__ Wp,      // [256, 2048] packed half2(k,k+1)
    __half* __restrict__ hout)       // [B*T, 512] f16
{
    __shared__ u32 sh[HH / 2];    // current h, packed f16 pairs
    __shared__ float zbuf[G4];
    const int tid = threadIdx.x;
    const int b = blockIdx.x;
    if (tid < HH / 2) sh[tid] = 0u;
    float cst = 0.0f;
    __syncthreads();

    const u32* wcol = Wp + (tid << 1);
    const u32* xwb = (const u32*)(xW + (size_t)b * TT * G4);

    for (int t = 0; t < TT; ++t) {
        __half2 acc0 = __float2half2_rn(0.0f);
        __half2 acc1 = __float2half2_rn(0.0f);
#pragma unroll 8
        for (int k2 = 0; k2 < HH / 2; ++k2) {
            __half2 hv = u2h(sh[k2]);
            uint2 w = *(const uint2*)(wcol + (size_t)k2 * G4);
            acc0 = __hfma2(hv, u2h(w.x), acc0);
            acc1 = __hfma2(hv, u2h(w.y), acc1);
        }
        u32 xwu = xwb[(size_t)t * (G4 / 2) + tid];
        __half2 xh = u2h(xwu);
        zbuf[2 * tid]     = __low2float(acc0) + __high2float(acc0) + __low2float(xh);
        zbuf[2 * tid + 1] = __low2float(acc1) + __high2float(acc1) + __high2float(xh);
        __syncthreads();
        if (tid < HH) {
            float zi = zbuf[tid];
            float zf = zbuf[tid + HH];
            float zg = zbuf[tid + 2 * HH];
            float zo = zbuf[tid + 3 * HH];
            float ii = sigm(zi), ff = sigm(zf), gg = tanh_fast(zg), oo = sigm(zo);
            cst = ff * cst + ii * gg;
            float hv = oo * tanh_fast(cst);
            __half hf = __float2half(hv);
            ((u16*)sh)[tid] = __half_as_ushort(hf);
            hout[(size_t)(b * TT + t) * HH + tid] = hf;
        }
        __syncthreads();
    }
}

// ---------------------------------------------------------------------------
// BatchNorm stats: accumulate sum and sum-of-squares per feature (512).
// Each block handles 128 rows; thread handles feature pair (2t, 2t+1).
// accum layout: [0..511]=sum, [512..1023]=sumsq.
// ---------------------------------------------------------------------------
__global__ __launch_bounds__(256) void bn_stats(
    const __half* __restrict__ h, float* __restrict__ accum)
{
    const int tid = threadIdx.x;
    const u32* hp = (const u32*)h;
    float s0 = 0, s1 = 0, q0 = 0, q1 = 0;
    int base = blockIdx.x * 128;
    for (int r = 0; r < 128; ++r) {
        u32 u = hp[(size_t)(base + r) * (HH / 2) + tid];
        __half2 v = u2h(u);
        float a = __low2float(v), b = __high2float(v);
        s0 += a; q0 += a * a; s1 += b; q1 += b * b;
    }
    atomicAdd(&accum[2 * tid], s0);
    atomicAdd(&accum[2 * tid + 1], s1);
    atomicAdd(&accum[HH + 2 * tid], q0);
    atomicAdd(&accum[HH + 2 * tid + 1], q1);
}

__global__ __launch_bounds__(512) void bn_finalize(
    const float* __restrict__ accum, const float* __restrict__ gamma,
    const float* __restrict__ beta, float* __restrict__ s, float* __restrict__ t)
{
    int j = threadIdx.x;
    const float inv = 1.0f / (float)(BB * TT);
    float m = accum[j] * inv;
    float v = accum[HH + j] * inv - m * m;
    float scv = gamma[j] * rsqrtf(v + 1e-5f);
    s[j] = scv;
    t[j] = beta[j] - m * scv;
}

// ---------------------------------------------------------------------------
// Head: out[m] = relu(bn(h2[m,:]) @ Wd1 + bd1) @ Wd2 + bd2
// 16 threads per row (one per Wd1 column), width-16 shuffle reduce.
// ---------------------------------------------------------------------------
__global__ __launch_bounds__(256) void head_kernel(
    const __half* __restrict__ h2, const float* __restrict__ s2,
    const float* __restrict__ t2, const float* __restrict__ Wd1,
    const float* __restrict__ bd1, const float* __restrict__ Wd2,
    const float* __restrict__ bd2, float* __restrict__ out)
{
    const int tid = threadIdx.x;
    const int j = tid & 15;
    const int row = blockIdx.x * 16 + (tid >> 4);
    const __half* hr = h2 + (size_t)row * HH;
    float acc = 0.0f;
    for (int k = 0; k < HH; ++k) {
        float a = __half2float(hr[k]) * s2[k] + t2[k];
        acc += a * Wd1[k * 16 + j];
    }
    float r = fmaxf(acc + bd1[j], 0.0f);
    float v = r * Wd2[j];
#pragma unroll
    for (int off = 8; off; off >>= 1) v += __shfl_down(v, off, 16);
    if (j == 0) out[row] = v + bd2[0];
}

// ---------------------------------------------------------------------------
extern "C" void kernel_launch(void* const* d_in, const int* in_sizes, int n_in,
                              void* d_out, int out_size, void* d_ws, size_t ws_size,
                              hipStream_t stream)
{
    const float* x   = (const float*)d_in[0];
    const float* Wx1 = (const float*)d_in[1];
    const float* Wh1 = (const float*)d_in[2];
    const float* b1  = (const float*)d_in[3];
    const float* g1  = (const float*)d_in[4];
    const float* be1 = (const float*)d_in[5];
    const float* Wx2 = (const float*)d_in[6];
    const float* Wh2 = (const float*)d_in[7];
    const float* b2  = (const float*)d_in[8];
    const float* g2  = (const float*)d_in[9];
    const float* be2 = (const float*)d_in[10];
    const float* Wd1 = (const float*)d_in[11];
    const float* bd1 = (const float*)d_in[12];
    const float* Wd2 = (const float*)d_in[13];
    const float* bd2 = (const float*)d_in[14];
    float* out = (float*)d_out;

    char* ws = (char*)d_ws;
    __half* xW   = (__half*)(ws);                      // 128 MiB  [B*T, 2048]
    __half* h1   = (__half*)(ws + 134217728);          // 32 MiB   [B*T, 512]
    __half* h2   = (__half*)(ws + 167772160);          // 32 MiB
    u32*    P1   = (u32*)   (ws + 201326592);          // 2 MiB
    u32*    P2   = (u32*)   (ws + 203423744);          // 2 MiB
    float*  accum= (float*) (ws + 205520896);          // 2048 f32 (layer1 @0, layer2 @1024)
    float*  s1   = (float*) (ws + 205529088);
    float*  t1   = s1 + HH;
    float*  s2   = t1 + HH;
    float*  t2   = s2 + HH;

    const int M = BB * TT;  // 32768

    pack_wh<<<2048, 256, 0, stream>>>(Wh1, Wh2, P1, P2, accum);

    gemm64<false, false><<<dim3(G4 / 64, M / 64), 256, 0, stream>>>(
        x, Wx1, b1, nullptr, nullptr, xW, M, G4, FF);

    lstm_scan<<<BB, 1024, 0, stream>>>(xW, P1, h1);

    bn_stats<<<256, 256, 0, stream>>>(h1, accum);
    bn_finalize<<<1, 512, 0, stream>>>(accum, g1, be1, s1, t1);

    gemm64<true, true><<<dim3(G4 / 64, M / 64), 256, 0, stream>>>(
        h1, Wx2, b2, s1, t1, xW, M, G4, HH);

    lstm_scan<<<BB, 1024, 0, stream>>>(xW, P2, h2);

    bn_stats<<<256, 256, 0, stream>>>(h2, accum + 1024);
    bn_finalize<<<1, 512, 0, stream>>>(accum + 1024, g2, be2, s2, t2);

    head_kernel<<<M / 16, 256, 0, stream>>>(h2, s2, t2, Wd1, bd1, Wd2, bd2, out);
}

// Round 2
// 19315.092 us; speedup vs baseline: 1.6006x; 1.6006x over previous
//
#include <hip/hip_runtime.h>
#include <hip/hip_fp16.h>

typedef unsigned int u32;
typedef unsigned short u16;

#define BB 64
#define TT 512
#define FF 128
#define HH 512
#define G4 2048  // 4*H

typedef _Float16 f16x8 __attribute__((ext_vector_type(8)));
typedef float f32x4 __attribute__((ext_vector_type(4)));

union UH2 { u32 u; __half2 h; };
__device__ inline __half2 u2h(u32 u) { UH2 t; t.u = u; return t.h; }

__device__ inline float sigm(float x) { return 1.0f / (1.0f + __expf(-x)); }
__device__ inline float tanh_fast(float x) { return 2.0f / (1.0f + __expf(-2.0f * x)) - 1.0f; }

// ---------------------------------------------------------------------------
// Zero BN accumulators and barrier counters (ws is poisoned before each call).
// ---------------------------------------------------------------------------
__global__ __launch_bounds__(256) void zero_init(float* __restrict__ accum, u32* __restrict__ cnt)
{
    int tid = threadIdx.x;
    for (int i = tid; i < 2048; i += 256) accum[i] = 0.0f;
    if (tid < 128) cnt[tid] = 0u;
}

// ---------------------------------------------------------------------------
// Tiled fp32 GEMM: C(f16)[M,N] = A[M,K] @ B[K,N] + bias[N]
// A either f32 or f16; optional per-k affine on A (folded BatchNorm).
// ---------------------------------------------------------------------------
template <bool A_HALF, bool AFFINE>
__global__ __launch_bounds__(256) void gemm64(
    const void* __restrict__ Av, const float* __restrict__ B,
    const float* __restrict__ bias, const float* __restrict__ sc,
    const float* __restrict__ tr, __half* __restrict__ C,
    int M, int N, int K)
{
    __shared__ float sA[16][64];
    __shared__ float sB[16][64];
    const int tid = threadIdx.x;
    const int tx = tid & 15, ty = tid >> 4;
    const int bm = blockIdx.y << 6, bn = blockIdx.x << 6;
    const int lm = tid >> 2, lk = (tid & 3) << 2;
    const int br = tid >> 6, bc = tid & 63;
    float acc[4][4] = {};

    for (int k0 = 0; k0 < K; k0 += 16) {
        float av[4];
        if constexpr (A_HALF) {
            const __half* A = (const __half*)Av + (size_t)(bm + lm) * K + (k0 + lk);
            uint2 u = *(const uint2*)A;
            __half2 p0 = u2h(u.x), p1 = u2h(u.y);
            av[0] = __low2float(p0); av[1] = __high2float(p0);
            av[2] = __low2float(p1); av[3] = __high2float(p1);
        } else {
            const float4 v = *(const float4*)((const float*)Av + (size_t)(bm + lm) * K + (k0 + lk));
            av[0] = v.x; av[1] = v.y; av[2] = v.z; av[3] = v.w;
        }
        if constexpr (AFFINE) {
#pragma unroll
            for (int i = 0; i < 4; ++i) av[i] = av[i] * sc[k0 + lk + i] + tr[k0 + lk + i];
        }
#pragma unroll
        for (int i = 0; i < 4; ++i) sA[lk + i][lm] = av[i];
#pragma unroll
        for (int i = 0; i < 4; ++i)
            sB[br + 4 * i][bc] = B[(size_t)(k0 + br + 4 * i) * N + bn + bc];
        __syncthreads();
#pragma unroll
        for (int kk = 0; kk < 16; ++kk) {
            const float4 a4 = *(const float4*)&sA[kk][ty << 2];
            const float4 b4 = *(const float4*)&sB[kk][tx << 2];
            float aa[4] = {a4.x, a4.y, a4.z, a4.w};
            float bb[4] = {b4.x, b4.y, b4.z, b4.w};
#pragma unroll
            for (int i = 0; i < 4; ++i)
#pragma unroll
                for (int j = 0; j < 4; ++j) acc[i][j] += aa[i] * bb[j];
        }
        __syncthreads();
    }
#pragma unroll
    for (int i = 0; i < 4; ++i) {
        u16 q[4];
#pragma unroll
        for (int j = 0; j < 4; ++j) {
            float v = acc[i][j] + bias[bn + (tx << 2) + j];
            q[j] = __half_as_ushort(__float2half(v));
        }
        uint2 st;
        st.x = (u32)q[0] | ((u32)q[1] << 16);
        st.y = (u32)q[2] | ((u32)q[3] << 16);
        *(uint2*)(C + (size_t)(bm + (ty << 2) + i) * N + bn + (tx << 2)) = st;
    }
}

// ---------------------------------------------------------------------------
// MFMA LSTM scan, weight-stationary in LDS.
// Grid: 256 blocks = 4 batch-chains (bg) x 64 col-blocks (cb). 128 threads.
// Block owns batch rows [16*bg, 16*bg+16) and hidden cols [8*cb, 8*cb+8)
// (i.e. 32 gate columns: gate g at global col g*512 + cb*8 + hl).
// Wh slice (512 x 32 f16, frag-ordered) stays in LDS the whole scan.
// Per step: stage h_{t-1}[16,512] -> LDS, 2 waves x 16 MFMA(16x16x32_f16),
// gate update (c in reg), agent-scope h store, per-chain spin barrier.
// BN stats fused (block owns its cols; atomicAdd across the 4 chains).
// ---------------------------------------------------------------------------
__global__ __launch_bounds__(128) void lstm_scan_mfma(
    const __half* __restrict__ xW,   // [B*T, 2048] f16 (x@Wx + b)
    const float* __restrict__ Wh,    // [512, 2048] f32
    __half* __restrict__ hout,       // [B*T, 512] f16
    u32* __restrict__ cnt,           // 4 chains x 16 u32 spacing
    float* __restrict__ accum)       // [sum 512][sumsq 512]
{
    __shared__ _Float16 wl[16384];       // 32 KB: [kt 16][gc 32][kg 4][j 8]
    __shared__ _Float16 shh[16 * 520];   // 16.6 KB: h rows, stride 520 halves
    __shared__ float zbuf[16 * 33];      // 2.1 KB: z tile [m 16][gc 32+1]

    const int tid = threadIdx.x;
    const int cb = blockIdx.x & 63;
    const int bg = blockIdx.x >> 6;
    u32* mycnt = cnt + bg * 16;

    // ---- one-time: load Wh slice f32 -> f16 frag layout in LDS ----
    for (int it = 0; it < 64; ++it) {
        int idx = it * 128 + tid;            // 8192 = 512 k * 16 col-pairs
        int k = idx >> 4, pr = idx & 15;
        int gc = pr << 1;
        int gate = gc >> 3, hl = gc & 7;
        const float* wp = Wh + (size_t)k * G4 + gate * 512 + cb * 8 + hl;
        float w0 = wp[0], w1 = wp[1];
        int f = (((k >> 5) * 32 + gc) * 4 + ((k >> 3) & 3)) * 8 + (k & 7);
        wl[f] = (_Float16)w0;
        wl[f + 32] = (_Float16)w1;
    }

    // update-phase identity: one (batch,hcol) state per thread
    const int ub = tid >> 3;          // 0..15 local batch row
    const int uh = tid & 7;           // 0..7 local hidden col
    const size_t grow = ((size_t)(bg * 16 + ub)) * TT;   // row base in [B*T]
    const int gcol0 = cb * 8 + uh;    // global hidden col

    // MFMA identities
    const int l = tid & 63, nw = tid >> 6;          // lane, wave(=N-tile)
    const int am = l & 15, kg = l >> 4;             // frag row, k-group
    const _Float16* ap0 = shh + am * 520 + kg * 8;
    const _Float16* bp0 = wl + (((nw * 16 + am) * 4 + kg) * 8);
    // staging identity
    const int srow = tid >> 3, schunk = tid & 7;
    _Float16* sdst = shh + srow * 520;

    float cst = 0.0f, ssum = 0.0f, ssq = 0.0f;
    __syncthreads();

    for (int t = 0; t < TT; ++t) {
        // prefetch xW for this step (independent of barrier/staging)
        const __half* xp = xW + (grow + t) * G4 + gcol0;
        float xwv0 = __half2float(xp[0]);
        float xwv1 = __half2float(xp[512]);
        float xwv2 = __half2float(xp[1024]);
        float xwv3 = __half2float(xp[1536]);

        if (t > 0) {
            // stage h_{t-1}[16 rows, 512] -> shh (coalesced 16B chunks)
            const uint4* hp = (const uint4*)(hout + ((size_t)(bg * 16 + srow) * TT + (t - 1)) * HH);
#pragma unroll
            for (int j = 0; j < 8; ++j) {
                int idx = schunk + 8 * j;       // 0..63 uint4 per row
                *(uint4*)(sdst + idx * 8) = hp[idx];
            }
        }
        __syncthreads();

        if (t > 0) {
            f32x4 acc = {0.0f, 0.0f, 0.0f, 0.0f};
#pragma unroll
            for (int kt = 0; kt < 16; ++kt) {
                f16x8 a = *(const f16x8*)(ap0 + kt * 32);
                f16x8 b = *(const f16x8*)(bp0 + kt * 1024);
                acc = __builtin_amdgcn_mfma_f32_16x16x32_f16(a, b, acc, 0, 0, 0);
            }
#pragma unroll
            for (int r = 0; r < 4; ++r)
                zbuf[(kg * 4 + r) * 33 + nw * 16 + am] = acc[r];
        }
        __syncthreads();

        // ---- gate update ----
        float z0 = xwv0, z1 = xwv1, z2 = xwv2, z3 = xwv3;
        if (t > 0) {
            z0 += zbuf[ub * 33 + 0 * 8 + uh];
            z1 += zbuf[ub * 33 + 1 * 8 + uh];
            z2 += zbuf[ub * 33 + 2 * 8 + uh];
            z3 += zbuf[ub * 33 + 3 * 8 + uh];
        }
        float ii = sigm(z0), ff = sigm(z1), gg = tanh_fast(z2), oo = sigm(z3);
        cst = ff * cst + ii * gg;
        float hval = oo * tanh_fast(cst);
        ssum += hval; ssq += hval * hval;

        // pack pair and store (agent scope -> visible cross-XCD)
        float hnb = __shfl_down(hval, 1);
        if ((tid & 1) == 0) {
            u16 h0 = __half_as_ushort(__float2half(hval));
            u16 h1 = __half_as_ushort(__float2half(hnb));
            u32 pk = (u32)h0 | ((u32)h1 << 16);
            u32* dst = (u32*)(hout + (grow + t) * HH + gcol0);
            __hip_atomic_store(dst, pk, __ATOMIC_RELAXED, __HIP_MEMORY_SCOPE_AGENT);
        }
        __syncthreads();   // zbuf consumed; h stores drained (vmcnt0)

        if (tid == 0) {
            __threadfence();   // L2 writeback to coherence point
            __hip_atomic_fetch_add(mycnt, 1u, __ATOMIC_RELEASE, __HIP_MEMORY_SCOPE_AGENT);
            u32 target = 64u * (u32)(t + 1);
            while (__hip_atomic_load(mycnt, __ATOMIC_ACQUIRE, __HIP_MEMORY_SCOPE_AGENT) < target)
                __builtin_amdgcn_s_sleep(2);
        }
        __syncthreads();
    }

    // ---- fused BN stats: reduce over local batch, atomicAdd across chains ----
    float* red = zbuf;
    red[tid] = ssum;
    __syncthreads();
    if (tid < 8) {
        float s = 0.0f;
#pragma unroll
        for (int b = 0; b < 16; ++b) s += red[b * 8 + tid];
        atomicAdd(&accum[cb * 8 + tid], s);
    }
    __syncthreads();
    red[tid] = ssq;
    __syncthreads();
    if (tid < 8) {
        float s = 0.0f;
#pragma unroll
        for (int b = 0; b < 16; ++b) s += red[b * 8 + tid];
        atomicAdd(&accum[HH + cb * 8 + tid], s);
    }
}

__global__ __launch_bounds__(512) void bn_finalize(
    const float* __restrict__ accum, const float* __restrict__ gamma,
    const float* __restrict__ beta, float* __restrict__ s, float* __restrict__ t)
{
    int j = threadIdx.x;
    const float inv = 1.0f / (float)(BB * TT);
    float m = accum[j] * inv;
    float v = accum[HH + j] * inv - m * m;
    float scv = gamma[j] * rsqrtf(v + 1e-5f);
    s[j] = scv;
    t[j] = beta[j] - m * scv;
}

// ---------------------------------------------------------------------------
// Head: out[m] = relu(bn(h2[m,:]) @ Wd1 + bd1) @ Wd2 + bd2
// ---------------------------------------------------------------------------
__global__ __launch_bounds__(256) void head_kernel(
    const __half* __restrict__ h2, const float* __restrict__ s2,
    const float* __restrict__ t2, const float* __restrict__ Wd1,
    const float* __restrict__ bd1, const float* __restrict__ Wd2,
    const float* __restrict__ bd2, float* __restrict__ out)
{
    const int tid = threadIdx.x;
    const int j = tid & 15;
    const int row = blockIdx.x * 16 + (tid >> 4);
    const __half* hr = h2 + (size_t)row * HH;
    float acc = 0.0f;
    for (int k = 0; k < HH; ++k) {
        float a = __half2float(hr[k]) * s2[k] + t2[k];
        acc += a * Wd1[k * 16 + j];
    }
    float r = fmaxf(acc + bd1[j], 0.0f);
    float v = r * Wd2[j];
#pragma unroll
    for (int off = 8; off; off >>= 1) v += __shfl_down(v, off, 16);
    if (j == 0) out[row] = v + bd2[0];
}

// ---------------------------------------------------------------------------
extern "C" void kernel_launch(void* const* d_in, const int* in_sizes, int n_in,
                              void* d_out, int out_size, void* d_ws, size_t ws_size,
                              hipStream_t stream)
{
    const float* x   = (const float*)d_in[0];
    const float* Wx1 = (const float*)d_in[1];
    const float* Wh1 = (const float*)d_in[2];
    const float* b1  = (const float*)d_in[3];
    const float* g1  = (const float*)d_in[4];
    const float* be1 = (const float*)d_in[5];
    const float* Wx2 = (const float*)d_in[6];
    const float* Wh2 = (const float*)d_in[7];
    const float* b2  = (const float*)d_in[8];
    const float* g2  = (const float*)d_in[9];
    const float* be2 = (const float*)d_in[10];
    const float* Wd1 = (const float*)d_in[11];
    const float* bd1 = (const float*)d_in[12];
    const float* Wd2 = (const float*)d_in[13];
    const float* bd2 = (const float*)d_in[14];
    float* out = (float*)d_out;

    char* ws = (char*)d_ws;
    __half* xW    = (__half*)(ws);                   // 128 MiB  [B*T, 2048]
    __half* h1    = (__half*)(ws + 134217728);       // 32 MiB   [B*T, 512]
    __half* h2    = (__half*)(ws + 167772160);       // 32 MiB
    float*  accum = (float*) (ws + 201326592);       // 2048 f32 (layer1 @0, layer2 @1024)
    u32*    cnt   = (u32*)   (ws + 201334784);       // 128 u32 barrier counters
    float*  s1    = (float*) (ws + 201335296);
    float*  t1    = s1 + HH;
    float*  s2    = t1 + HH;
    float*  t2    = s2 + HH;

    const int M = BB * TT;  // 32768

    zero_init<<<1, 256, 0, stream>>>(accum, cnt);

    gemm64<false, false><<<dim3(G4 / 64, M / 64), 256, 0, stream>>>(
        x, Wx1, b1, nullptr, nullptr, xW, M, G4, FF);

    lstm_scan_mfma<<<256, 128, 0, stream>>>(xW, Wh1, h1, cnt, accum);
    bn_finalize<<<1, 512, 0, stream>>>(accum, g1, be1, s1, t1);

    gemm64<true, true><<<dim3(G4 / 64, M / 64), 256, 0, stream>>>(
        h1, Wx2, b2, s1, t1, xW, M, G4, HH);

    lstm_scan_mfma<<<256, 128, 0, stream>>>(xW, Wh2, h2, cnt + 64, accum + 1024);
    bn_finalize<<<1, 512, 0, stream>>>(accum + 1024, g2, be2, s2, t2);

    head_kernel<<<M / 16, 256, 0, stream>>>(h2, s2, t2, Wd1, bd1, Wd2, bd2, out);
}

// Round 3
// 6663.239 us; speedup vs baseline: 4.6397x; 2.8988x over previous
//
#include <hip/hip_runtime.h>
#include <hip/hip_fp16.h>

typedef unsigned int u32;
typedef unsigned short u16;

#define BB 64
#define TT 512
#define FF 128
#define HH 512
#define G4 2048  // 4*H

typedef _Float16 f16x8 __attribute__((ext_vector_type(8)));
typedef float f32x4 __attribute__((ext_vector_type(4)));

__device__ inline float sigm(float x) { return 1.0f / (1.0f + __expf(-x)); }
__device__ inline float tanh_fast(float x) { return 2.0f / (1.0f + __expf(-2.0f * x)) - 1.0f; }

// ---------------------------------------------------------------------------
// Zero BN accumulators and barrier counters (ws is poisoned before each call).
// ---------------------------------------------------------------------------
__global__ __launch_bounds__(256) void zero_init(float* __restrict__ accum, u32* __restrict__ cnt)
{
    int tid = threadIdx.x;
    for (int i = tid; i < 2048; i += 256) accum[i] = 0.0f;
    if (tid < 128) cnt[tid] = 0u;
}

// ---------------------------------------------------------------------------
// MFMA f16 GEMM: C(f16)[M,2048] = A[M,K] @ B[K,2048] + bias.
// BM=BN=128, BK=32, 256 threads (4 waves in 2x2), 4x4 16x16x32 tiles/wave.
// A f32 or f16; optional per-k affine on A (folded BatchNorm).
// LDS frag layouts, stride 40 halves (16B aligned, spread banks).
// ---------------------------------------------------------------------------
template <bool A_HALF, bool AFFINE>
__global__ __launch_bounds__(256) void gemm_mfma(
    const void* __restrict__ Av, const float* __restrict__ Bw,
    const float* __restrict__ bias, const float* __restrict__ sc,
    const float* __restrict__ tr, __half* __restrict__ C, int K)
{
    __shared__ _Float16 sA[128 * 40];
    __shared__ _Float16 sB[128 * 40];
    const int tid = threadIdx.x;
    const int bn = blockIdx.x << 7;
    const int bm = blockIdx.y << 7;
    const int w = tid >> 6, l = tid & 63;
    const int mq = w >> 1, nq = w & 1;
    const int am = l & 15, kg = l >> 4;

    const _Float16* apb = sA + (mq * 64 + am) * 40 + kg * 8;
    const _Float16* bpb = sB + (nq * 64 + am) * 40 + kg * 8;

    const int ar = tid >> 1, akc = (tid & 1) * 16;
    const int bnn = tid & 127, bkr = (tid >> 7) * 16;

    f32x4 acc[4][4];
#pragma unroll
    for (int i = 0; i < 4; ++i)
#pragma unroll
        for (int j = 0; j < 4; ++j) acc[i][j] = (f32x4){0.f, 0.f, 0.f, 0.f};

    for (int k0 = 0; k0 < K; k0 += 32) {
        // ---- stage A tile [128 m][32 k] ----
        {
            float av[16];
            if constexpr (A_HALF) {
                const __half* Ap = (const __half*)Av + (size_t)(bm + ar) * K + k0 + akc;
                __half tmp[16];
                *(uint4*)&tmp[0] = *(const uint4*)Ap;
                *(uint4*)&tmp[8] = *(const uint4*)(Ap + 8);
#pragma unroll
                for (int i = 0; i < 16; ++i) av[i] = __half2float(tmp[i]);
            } else {
                const float* Ap = (const float*)Av + (size_t)(bm + ar) * K + k0 + akc;
#pragma unroll
                for (int i = 0; i < 16; i += 4) {
                    float4 v = *(const float4*)(Ap + i);
                    av[i] = v.x; av[i + 1] = v.y; av[i + 2] = v.z; av[i + 3] = v.w;
                }
            }
            if constexpr (AFFINE) {
#pragma unroll
                for (int i = 0; i < 16; ++i) av[i] = av[i] * sc[k0 + akc + i] + tr[k0 + akc + i];
            }
            _Float16 st[16];
#pragma unroll
            for (int i = 0; i < 16; ++i) st[i] = (_Float16)av[i];
            *(f16x8*)(sA + ar * 40 + akc) = *(f16x8*)&st[0];
            *(f16x8*)(sA + ar * 40 + akc + 8) = *(f16x8*)&st[8];
        }
        // ---- stage B tile [32 k][128 n] transposed into [n][k] ----
        {
            _Float16 st[16];
#pragma unroll
            for (int i = 0; i < 16; ++i)
                st[i] = (_Float16)Bw[(size_t)(k0 + bkr + i) * G4 + bn + bnn];
            *(f16x8*)(sB + bnn * 40 + bkr) = *(f16x8*)&st[0];
            *(f16x8*)(sB + bnn * 40 + bkr + 8) = *(f16x8*)&st[8];
        }
        __syncthreads();
        f16x8 af[4], bf[4];
#pragma unroll
        for (int i = 0; i < 4; ++i) af[i] = *(const f16x8*)(apb + i * 16 * 40);
#pragma unroll
        for (int j = 0; j < 4; ++j) bf[j] = *(const f16x8*)(bpb + j * 16 * 40);
#pragma unroll
        for (int i = 0; i < 4; ++i)
#pragma unroll
            for (int j = 0; j < 4; ++j)
                acc[i][j] = __builtin_amdgcn_mfma_f32_16x16x32_f16(af[i], bf[j], acc[i][j], 0, 0, 0);
        __syncthreads();
    }

    // ---- epilogue: +bias, f16, packed u32 stores ----
#pragma unroll
    for (int i = 0; i < 4; ++i) {
        const int row0 = bm + mq * 64 + i * 16 + kg * 4;
#pragma unroll
        for (int j = 0; j < 4; ++j) {
            const int col = bn + nq * 64 + j * 16 + am;
            const float bv = bias[col];
#pragma unroll
            for (int r = 0; r < 4; ++r) {
                float v = acc[i][j][r] + bv;
                u32 hu = (u32)__half_as_ushort(__float2half(v));
                u32 hn = __shfl_down(hu, 1);
                if ((am & 1) == 0) {
                    u32 pk = hu | (hn << 16);
                    *(u32*)(C + (size_t)(row0 + r) * G4 + col) = pk;
                }
            }
        }
    }
}

// ---------------------------------------------------------------------------
// MFMA LSTM scan, weight-stationary in REGISTERS.
// Grid: 64 blocks = 4 chains (bg) x 16 col-blocks (cb), 512 threads (8 waves).
// Block owns batch rows [16*bg,+16) and hidden cols [32*cb,+32) (128 gate
// cols). Wave w owns 16 gate cols: gate g=w>>1, hl=(w&1)*16+(lane&15);
// its B-slice (512 x 16 f16) lives in 16 f16x8 VGPR frags, loaded once.
// Per step: stage h[16,512] -> LDS (A-frag order), 16 MFMA/wave, gate
// update (c in reg), agent-scope h store, relaxed arrive + relaxed spin +
// one acquire (invalidate-only) fence. NO wbl2 anywhere. BN stats fused.
// ---------------------------------------------------------------------------
__global__ __launch_bounds__(512, 2) void lstm_scan_mfma(
    const __half* __restrict__ xW,   // [B*T, 2048] f16 (x@Wx + b)
    const float* __restrict__ Wh,    // [512, 2048] f32
    __half* __restrict__ hout,       // [B*T, 512] f16
    u32* __restrict__ cnt,           // 4 chains x 16-u32 spacing
    float* __restrict__ accum)       // [sum 512][sumsq 512]
{
    __shared__ _Float16 shh[8192];     // 16 KB: A-frag order [kt16][m16][kg4][j8]
    __shared__ float zbuf[16 * 132];   // 8.4 KB: z tile [m16][gc128 +4]

    const int tid = threadIdx.x;
    const int cb = blockIdx.x & 15;
    const int bg = blockIdx.x >> 4;
    u32* mycnt = cnt + bg * 16;

    const int w = tid >> 6, l = tid & 63;
    const int am = l & 15, kq = l >> 4;

    // ---- one-time: load wave's B-slice into registers (f32 -> f16) ----
    const int gcol_b = (w >> 1) * 512 + cb * 32 + (w & 1) * 16 + am;
    f16x8 bfr[16];
#pragma unroll
    for (int kt = 0; kt < 16; ++kt) {
        _Float16 tmp[8];
#pragma unroll
        for (int j = 0; j < 8; ++j)
            tmp[j] = (_Float16)Wh[(size_t)(kt * 32 + kq * 8 + j) * G4 + gcol_b];
        bfr[kt] = *(f16x8*)tmp;
    }

    // update-phase identity: thread owns (batch ub, hidden col uh)
    const int ub = tid >> 5, uh = tid & 31;
    const size_t growT = (size_t)(bg * 16 + ub) * TT;
    const int gcol0 = cb * 32 + uh;

    float cst = 0.0f, ssum = 0.0f, ssq = 0.0f;

    for (int t = 0; t < TT; ++t) {
        // prefetch xW gates for this step
        const __half* xp = xW + (growT + t) * G4 + gcol0;
        float xw0 = __half2float(xp[0]);
        float xw1 = __half2float(xp[512]);
        float xw2 = __half2float(xp[1024]);
        float xw3 = __half2float(xp[1536]);

        if (t > 0) {
            // stage h_{t-1}[16,512] -> shh in A-frag order (2 x 16B per thread)
#pragma unroll
            for (int hh = 0; hh < 2; ++hh) {
                int c = tid + hh * 512;           // 0..1023 chunks of 8 halves
                int m = c >> 6, q = c & 63;
                uint4 v = *((const uint4*)(hout + ((size_t)(bg * 16 + m) * TT + (t - 1)) * HH) + q);
                *(uint4*)(shh + (q >> 2) * 512 + m * 32 + (q & 3) * 8) = v;
            }
        }
        __syncthreads();

        if (t > 0) {
            f32x4 acc = {0.f, 0.f, 0.f, 0.f};
#pragma unroll
            for (int kt = 0; kt < 16; ++kt) {
                f16x8 a = *(const f16x8*)(shh + kt * 512 + am * 32 + kq * 8);
                acc = __builtin_amdgcn_mfma_f32_16x16x32_f16(a, bfr[kt], acc, 0, 0, 0);
            }
#pragma unroll
            for (int r = 0; r < 4; ++r)
                zbuf[(kq * 4 + r) * 132 + w * 16 + am] = acc[r];
        }
        __syncthreads();

        // ---- gate update ----
        float z0 = xw0, z1 = xw1, z2 = xw2, z3 = xw3;
        if (t > 0) {
            z0 += zbuf[ub * 132 + uh];
            z1 += zbuf[ub * 132 + 32 + uh];
            z2 += zbuf[ub * 132 + 64 + uh];
            z3 += zbuf[ub * 132 + 96 + uh];
        }
        float ii = sigm(z0), ff = sigm(z1), gg = tanh_fast(z2), oo = sigm(z3);
        cst = ff * cst + ii * gg;
        float hval = oo * tanh_fast(cst);
        ssum += hval; ssq += hval * hval;

        // publish h (agent scope, write-through to LLC)
        u32 hu = (u32)__half_as_ushort(__float2half(hval));
        u32 hn = __shfl_down(hu, 1);
        if ((tid & 1) == 0) {
            u32 pk = hu | (hn << 16);
            u32* dst = (u32*)(hout + (growT + t) * HH + gcol0);
            __hip_atomic_store(dst, pk, __ATOMIC_RELAXED, __HIP_MEMORY_SCOPE_AGENT);
        }
        __syncthreads();   // each wave drains vmcnt before barrier -> h visible

        if (tid == 0) {
            __hip_atomic_fetch_add(mycnt, 1u, __ATOMIC_RELAXED, __HIP_MEMORY_SCOPE_AGENT);
            u32 target = 16u * (u32)(t + 1);
            while (__hip_atomic_load(mycnt, __ATOMIC_RELAXED, __HIP_MEMORY_SCOPE_AGENT) < target)
                __builtin_amdgcn_s_sleep(1);
        }
        __syncthreads();
        // invalidate-only acquire before consuming other blocks' h
        __builtin_amdgcn_fence(__ATOMIC_ACQUIRE, "agent");
    }

    // ---- fused BN stats ----
    float* red = zbuf;
    red[tid] = ssum;
    __syncthreads();
    if (tid < 32) {
        float s = 0.f;
#pragma unroll
        for (int b = 0; b < 16; ++b) s += red[b * 32 + tid];
        atomicAdd(&accum[cb * 32 + tid], s);
    }
    __syncthreads();
    red[tid] = ssq;
    __syncthreads();
    if (tid < 32) {
        float s = 0.f;
#pragma unroll
        for (int b = 0; b < 16; ++b) s += red[b * 32 + tid];
        atomicAdd(&accum[HH + cb * 32 + tid], s);
    }
}

__global__ __launch_bounds__(512) void bn_finalize(
    const float* __restrict__ accum, const float* __restrict__ gamma,
    const float* __restrict__ beta, float* __restrict__ s, float* __restrict__ t)
{
    int j = threadIdx.x;
    const float inv = 1.0f / (float)(BB * TT);
    float m = accum[j] * inv;
    float v = accum[HH + j] * inv - m * m;
    float scv = gamma[j] * rsqrtf(v + 1e-5f);
    s[j] = scv;
    t[j] = beta[j] - m * scv;
}

// ---------------------------------------------------------------------------
// Head: out[m] = relu(bn(h2[m,:]) @ Wd1 + bd1) @ Wd2 + bd2
// ---------------------------------------------------------------------------
__global__ __launch_bounds__(256) void head_kernel(
    const __half* __restrict__ h2, const float* __restrict__ s2,
    const float* __restrict__ t2, const float* __restrict__ Wd1,
    const float* __restrict__ bd1, const float* __restrict__ Wd2,
    const float* __restrict__ bd2, float* __restrict__ out)
{
    const int tid = threadIdx.x;
    const int j = tid & 15;
    const int row = blockIdx.x * 16 + (tid >> 4);
    const __half* hr = h2 + (size_t)row * HH;
    float acc = 0.0f;
    for (int k = 0; k < HH; ++k) {
        float a = __half2float(hr[k]) * s2[k] + t2[k];
        acc += a * Wd1[k * 16 + j];
    }
    float r = fmaxf(acc + bd1[j], 0.0f);
    float v = r * Wd2[j];
#pragma unroll
    for (int off = 8; off; off >>= 1) v += __shfl_down(v, off, 16);
    if (j == 0) out[row] = v + bd2[0];
}

// ---------------------------------------------------------------------------
extern "C" void kernel_launch(void* const* d_in, const int* in_sizes, int n_in,
                              void* d_out, int out_size, void* d_ws, size_t ws_size,
                              hipStream_t stream)
{
    const float* x   = (const float*)d_in[0];
    const float* Wx1 = (const float*)d_in[1];
    const float* Wh1 = (const float*)d_in[2];
    const float* b1  = (const float*)d_in[3];
    const float* g1  = (const float*)d_in[4];
    const float* be1 = (const float*)d_in[5];
    const float* Wx2 = (const float*)d_in[6];
    const float* Wh2 = (const float*)d_in[7];
    const float* b2  = (const float*)d_in[8];
    const float* g2  = (const float*)d_in[9];
    const float* be2 = (const float*)d_in[10];
    const float* Wd1 = (const float*)d_in[11];
    const float* bd1 = (const float*)d_in[12];
    const float* Wd2 = (const float*)d_in[13];
    const float* bd2 = (const float*)d_in[14];
    float* out = (float*)d_out;

    char* ws = (char*)d_ws;
    __half* xW    = (__half*)(ws);                   // 128 MiB  [B*T, 2048]
    __half* h1    = (__half*)(ws + 134217728);       // 32 MiB   [B*T, 512]
    __half* h2    = (__half*)(ws + 167772160);       // 32 MiB
    float*  accum = (float*) (ws + 201326592);       // 2048 f32
    u32*    cnt   = (u32*)   (ws + 201334784);       // 128 u32 barrier counters
    float*  s1    = (float*) (ws + 201335296);
    float*  t1    = s1 + HH;
    float*  s2    = t1 + HH;
    float*  t2    = s2 + HH;

    const int M = BB * TT;  // 32768

    zero_init<<<1, 256, 0, stream>>>(accum, cnt);

    gemm_mfma<false, false><<<dim3(16, M / 128), 256, 0, stream>>>(
        x, Wx1, b1, nullptr, nullptr, xW, FF);

    lstm_scan_mfma<<<64, 512, 0, stream>>>(xW, Wh1, h1, cnt, accum);
    bn_finalize<<<1, 512, 0, stream>>>(accum, g1, be1, s1, t1);

    gemm_mfma<true, true><<<dim3(16, M / 128), 256, 0, stream>>>(
        h1, Wx2, b2, s1, t1, xW, HH);

    lstm_scan_mfma<<<64, 512, 0, stream>>>(xW, Wh2, h2, cnt + 64, accum + 1024);
    bn_finalize<<<1, 512, 0, stream>>>(accum + 1024, g2, be2, s2, t2);

    head_kernel<<<M / 16, 256, 0, stream>>>(h2, s2, t2, Wd1, bd1, Wd2, bd2, out);
}

// Round 4
// 4252.069 us; speedup vs baseline: 7.2706x; 1.5671x over previous
//
#include <hip/hip_runtime.h>
#include <hip/hip_fp16.h>

typedef unsigned int u32;
typedef unsigned short u16;

#define BB 64
#define TT 512
#define FF 128
#define HH 512
#define G4 2048  // 4*H

typedef _Float16 f16x8 __attribute__((ext_vector_type(8)));
typedef float f32x4 __attribute__((ext_vector_type(4)));

union UH2 { u32 u; __half2 h; };
__device__ inline __half2 u2h(u32 u) { UH2 t; t.u = u; return t.h; }

__device__ inline float sigm(float x) { return 1.0f / (1.0f + __expf(-x)); }
__device__ inline float tanh_fast(float x) { return 2.0f / (1.0f + __expf(-2.0f * x)) - 1.0f; }

// ---------------------------------------------------------------------------
// Zero BN accumulators and barrier flags (ws is poisoned before each call).
// ---------------------------------------------------------------------------
__global__ __launch_bounds__(256) void zero_init(float* __restrict__ accum, u32* __restrict__ cnt)
{
    int tid = threadIdx.x;
    for (int i = tid; i < 2048; i += 256) accum[i] = 0.0f;
    for (int i = tid; i < 1024; i += 256) cnt[i] = 0u;
}

// ---------------------------------------------------------------------------
// MFMA f16 GEMM: C(f16)[M,2048] = A[M,K] @ B[K,2048] + bias.
// BM=BN=128, BK=32, 256 threads (4 waves in 2x2), 4x4 16x16x32 tiles/wave.
// ---------------------------------------------------------------------------
template <bool A_HALF, bool AFFINE>
__global__ __launch_bounds__(256) void gemm_mfma(
    const void* __restrict__ Av, const float* __restrict__ Bw,
    const float* __restrict__ bias, const float* __restrict__ sc,
    const float* __restrict__ tr, __half* __restrict__ C, int K)
{
    __shared__ _Float16 sA[128 * 40];
    __shared__ _Float16 sB[128 * 40];
    const int tid = threadIdx.x;
    const int bn = blockIdx.x << 7;
    const int bm = blockIdx.y << 7;
    const int w = tid >> 6, l = tid & 63;
    const int mq = w >> 1, nq = w & 1;
    const int am = l & 15, kg = l >> 4;

    const _Float16* apb = sA + (mq * 64 + am) * 40 + kg * 8;
    const _Float16* bpb = sB + (nq * 64 + am) * 40 + kg * 8;

    const int ar = tid >> 1, akc = (tid & 1) * 16;
    const int bnn = tid & 127, bkr = (tid >> 7) * 16;

    f32x4 acc[4][4];
#pragma unroll
    for (int i = 0; i < 4; ++i)
#pragma unroll
        for (int j = 0; j < 4; ++j) acc[i][j] = (f32x4){0.f, 0.f, 0.f, 0.f};

    for (int k0 = 0; k0 < K; k0 += 32) {
        {
            float av[16];
            if constexpr (A_HALF) {
                const __half* Ap = (const __half*)Av + (size_t)(bm + ar) * K + k0 + akc;
                __half tmp[16];
                *(uint4*)&tmp[0] = *(const uint4*)Ap;
                *(uint4*)&tmp[8] = *(const uint4*)(Ap + 8);
#pragma unroll
                for (int i = 0; i < 16; ++i) av[i] = __half2float(tmp[i]);
            } else {
                const float* Ap = (const float*)Av + (size_t)(bm + ar) * K + k0 + akc;
#pragma unroll
                for (int i = 0; i < 16; i += 4) {
                    float4 v = *(const float4*)(Ap + i);
                    av[i] = v.x; av[i + 1] = v.y; av[i + 2] = v.z; av[i + 3] = v.w;
                }
            }
            if constexpr (AFFINE) {
#pragma unroll
                for (int i = 0; i < 16; ++i) av[i] = av[i] * sc[k0 + akc + i] + tr[k0 + akc + i];
            }
            _Float16 st[16];
#pragma unroll
            for (int i = 0; i < 16; ++i) st[i] = (_Float16)av[i];
            *(f16x8*)(sA + ar * 40 + akc) = *(f16x8*)&st[0];
            *(f16x8*)(sA + ar * 40 + akc + 8) = *(f16x8*)&st[8];
        }
        {
            _Float16 st[16];
#pragma unroll
            for (int i = 0; i < 16; ++i)
                st[i] = (_Float16)Bw[(size_t)(k0 + bkr + i) * G4 + bn + bnn];
            *(f16x8*)(sB + bnn * 40 + bkr) = *(f16x8*)&st[0];
            *(f16x8*)(sB + bnn * 40 + bkr + 8) = *(f16x8*)&st[8];
        }
        __syncthreads();
        f16x8 af[4], bf[4];
#pragma unroll
        for (int i = 0; i < 4; ++i) af[i] = *(const f16x8*)(apb + i * 16 * 40);
#pragma unroll
        for (int j = 0; j < 4; ++j) bf[j] = *(const f16x8*)(bpb + j * 16 * 40);
#pragma unroll
        for (int i = 0; i < 4; ++i)
#pragma unroll
            for (int j = 0; j < 4; ++j)
                acc[i][j] = __builtin_amdgcn_mfma_f32_16x16x32_f16(af[i], bf[j], acc[i][j], 0, 0, 0);
        __syncthreads();
    }

#pragma unroll
    for (int i = 0; i < 4; ++i) {
        const int row0 = bm + mq * 64 + i * 16 + kg * 4;
#pragma unroll
        for (int j = 0; j < 4; ++j) {
            const int col = bn + nq * 64 + j * 16 + am;
            const float bv = bias[col];
#pragma unroll
            for (int r = 0; r < 4; ++r) {
                float v = acc[i][j][r] + bv;
                u32 hu = (u32)__half_as_ushort(__float2half(v));
                u32 hn = __shfl_down(hu, 1);
                if ((am & 1) == 0) {
                    u32 pk = hu | (hn << 16);
                    *(u32*)(C + (size_t)(row0 + r) * G4 + col) = pk;
                }
            }
        }
    }
}

// ---------------------------------------------------------------------------
// MFMA LSTM scan v3: weight-stationary in registers, flag-array barrier.
// Grid: 32 blocks = 4 chains (bg) x 8 col-blocks (cb), 512 threads (8 waves).
// Block owns batch rows [16*bg,+16) and hidden cols [64*cb,+64) (256 gate
// cols). Wave w holds 32 gate cols of Wh in 2x16 f16x8 VGPR frags.
// Per step: poll 8 flags (parallel lane loads, no RMW), acquire fence,
// stage h[16,512] -> LDS row-major stride 520 (bank-balanced both sides),
// 2x16 MFMA per wave, gate update (c in regs, 2 hcols/thread), sc1 h store,
// syncthreads drain, single flag store. BN stats fused.
// ---------------------------------------------------------------------------
__global__ __launch_bounds__(512, 2) void lstm_scan_mfma(
    const __half* __restrict__ xW,   // [B*T, 2048] f16 (x@Wx + b)
    const float* __restrict__ Wh,    // [512, 2048] f32
    __half* __restrict__ hout,       // [B*T, 512] f16
    u32* __restrict__ flags,         // 32 flags x 16-u32 spacing
    float* __restrict__ accum)       // [sum 512][sumsq 512]
{
    __shared__ _Float16 shh[16 * 520];   // 16.25 KB, row-major h, stride 520
    __shared__ float zbuf[16 * 260];     // 16.25 KB, z tile [m16][gc256 +4]

    const int tid = threadIdx.x;
    const int cb = blockIdx.x & 7;
    const int bg = blockIdx.x >> 3;

    const int w = tid >> 6, l = tid & 63;
    const int am = l & 15, kq = l >> 4;

    // ---- one-time: wave's 32 Wh cols -> registers (f32 -> f16) ----
    f16x8 bfr[2][16];
#pragma unroll
    for (int c = 0; c < 2; ++c) {
        const int gcol = (w >> 1) * 512 + cb * 64 + (w & 1) * 32 + c * 16 + am;
#pragma unroll
        for (int kt = 0; kt < 16; ++kt) {
            _Float16 tmp[8];
#pragma unroll
            for (int j = 0; j < 8; ++j)
                tmp[j] = (_Float16)Wh[(size_t)(kt * 32 + kq * 8 + j) * G4 + gcol];
            bfr[c][kt] = *(f16x8*)tmp;
        }
    }

    // update identity: thread owns (row ub, hcols 2uh, 2uh+1)
    const int ub = tid >> 5, uh = tid & 31;
    const size_t growT = (size_t)(bg * 16 + ub) * TT;

    // polling identity
    const u32* pollp = flags + (size_t)(bg * 8 + (l & 7)) * 16;
    u32* myflag = flags + (size_t)(bg * 8 + cb) * 16;

    float cst0 = 0.f, cst1 = 0.f;
    float ss0 = 0.f, ss1 = 0.f, sq0 = 0.f, sq1 = 0.f;

    for (int t = 0; t < TT; ++t) {
        // xW prefetch: 4 gates x packed pair (independent of barrier)
        const u32* xp = (const u32*)(xW + (growT + t) * G4) + cb * 32 + uh;
        u32 xi = xp[0], xf = xp[256], xg = xp[512], xo = xp[768];

        if (t > 0) {
            // ---- wait for all 8 col-blocks of this chain to publish h_{t-1} ----
            while (!__all((int)(__hip_atomic_load(pollp, __ATOMIC_RELAXED,
                                                  __HIP_MEMORY_SCOPE_AGENT) >= (u32)t))) {}
            __builtin_amdgcn_fence(__ATOMIC_ACQUIRE, "agent");

            // ---- stage h_{t-1}[16,512] -> shh row-major (2 x 16B per thread) ----
#pragma unroll
            for (int hh = 0; hh < 2; ++hh) {
                int c = tid + hh * 512;
                int m = c >> 6, q = c & 63;
                uint4 v = *((const uint4*)(hout + ((size_t)(bg * 16 + m) * TT + (t - 1)) * HH) + q);
                *(uint4*)(shh + m * 520 + q * 8) = v;
            }
            __syncthreads();

            // ---- MFMA: 2 independent 16-col chains ----
            f32x4 a0 = {0.f, 0.f, 0.f, 0.f}, a1 = {0.f, 0.f, 0.f, 0.f};
            const _Float16* ap = shh + am * 520 + kq * 8;
#pragma unroll
            for (int kt = 0; kt < 16; ++kt) {
                f16x8 av = *(const f16x8*)(ap + kt * 32);
                a0 = __builtin_amdgcn_mfma_f32_16x16x32_f16(av, bfr[0][kt], a0, 0, 0, 0);
                a1 = __builtin_amdgcn_mfma_f32_16x16x32_f16(av, bfr[1][kt], a1, 0, 0, 0);
            }
#pragma unroll
            for (int r = 0; r < 4; ++r) {
                zbuf[(kq * 4 + r) * 260 + w * 32 + am] = a0[r];
                zbuf[(kq * 4 + r) * 260 + w * 32 + 16 + am] = a1[r];
            }
            __syncthreads();
        }

        // ---- gate update, 2 hcols per thread ----
        __half2 hxi = u2h(xi), hxf = u2h(xf), hxg = u2h(xg), hxo = u2h(xo);
        float zi0 = __low2float(hxi), zi1 = __high2float(hxi);
        float zf0 = __low2float(hxf), zf1 = __high2float(hxf);
        float zg0 = __low2float(hxg), zg1 = __high2float(hxg);
        float zo0 = __low2float(hxo), zo1 = __high2float(hxo);
        if (t > 0) {
            const float* zr = zbuf + ub * 260 + 2 * uh;
            zi0 += zr[0];   zi1 += zr[1];
            zf0 += zr[64];  zf1 += zr[65];
            zg0 += zr[128]; zg1 += zr[129];
            zo0 += zr[192]; zo1 += zr[193];
        }
        float i0 = sigm(zi0), f0 = sigm(zf0), g0 = tanh_fast(zg0), o0 = sigm(zo0);
        float i1 = sigm(zi1), f1 = sigm(zf1), g1 = tanh_fast(zg1), o1 = sigm(zo1);
        cst0 = f0 * cst0 + i0 * g0;
        cst1 = f1 * cst1 + i1 * g1;
        float h0 = o0 * tanh_fast(cst0);
        float h1 = o1 * tanh_fast(cst1);
        ss0 += h0; sq0 += h0 * h0; ss1 += h1; sq1 += h1 * h1;

        // publish h (agent scope, write-through)
        u32 pk = (u32)__half_as_ushort(__float2half(h0)) |
                 ((u32)__half_as_ushort(__float2half(h1)) << 16);
        u32* dst = (u32*)(hout + (growT + t) * HH + cb * 64) + uh;
        __hip_atomic_store(dst, pk, __ATOMIC_RELAXED, __HIP_MEMORY_SCOPE_AGENT);

        __syncthreads();   // all waves drain vmcnt before barrier -> h visible
        if (tid == 0)
            __hip_atomic_store(myflag, (u32)(t + 1), __ATOMIC_RELAXED, __HIP_MEMORY_SCOPE_AGENT);
    }

    // ---- fused BN stats ----
    float* red = zbuf;
    red[ub * 64 + 2 * uh] = ss0;
    red[ub * 64 + 2 * uh + 1] = ss1;
    __syncthreads();
    if (tid < 64) {
        float s = 0.f;
#pragma unroll
        for (int b = 0; b < 16; ++b) s += red[b * 64 + tid];
        atomicAdd(&accum[cb * 64 + tid], s);
    }
    __syncthreads();
    red[ub * 64 + 2 * uh] = sq0;
    red[ub * 64 + 2 * uh + 1] = sq1;
    __syncthreads();
    if (tid < 64) {
        float s = 0.f;
#pragma unroll
        for (int b = 0; b < 16; ++b) s += red[b * 64 + tid];
        atomicAdd(&accum[HH + cb * 64 + tid], s);
    }
}

__global__ __launch_bounds__(512) void bn_finalize(
    const float* __restrict__ accum, const float* __restrict__ gamma,
    const float* __restrict__ beta, float* __restrict__ s, float* __restrict__ t)
{
    int j = threadIdx.x;
    const float inv = 1.0f / (float)(BB * TT);
    float m = accum[j] * inv;
    float v = accum[HH + j] * inv - m * m;
    float scv = gamma[j] * rsqrtf(v + 1e-5f);
    s[j] = scv;
    t[j] = beta[j] - m * scv;
}

// ---------------------------------------------------------------------------
// Head: out[m] = relu(bn(h2[m,:]) @ Wd1 + bd1) @ Wd2 + bd2
// ---------------------------------------------------------------------------
__global__ __launch_bounds__(256) void head_kernel(
    const __half* __restrict__ h2, const float* __restrict__ s2,
    const float* __restrict__ t2, const float* __restrict__ Wd1,
    const float* __restrict__ bd1, const float* __restrict__ Wd2,
    const float* __restrict__ bd2, float* __restrict__ out)
{
    const int tid = threadIdx.x;
    const int j = tid & 15;
    const int row = blockIdx.x * 16 + (tid >> 4);
    const __half* hr = h2 + (size_t)row * HH;
    float acc = 0.0f;
    for (int k = 0; k < HH; ++k) {
        float a = __half2float(hr[k]) * s2[k] + t2[k];
        acc += a * Wd1[k * 16 + j];
    }
    float r = fmaxf(acc + bd1[j], 0.0f);
    float v = r * Wd2[j];
#pragma unroll
    for (int off = 8; off; off >>= 1) v += __shfl_down(v, off, 16);
    if (j == 0) out[row] = v + bd2[0];
}

// ---------------------------------------------------------------------------
extern "C" void kernel_launch(void* const* d_in, const int* in_sizes, int n_in,
                              void* d_out, int out_size, void* d_ws, size_t ws_size,
                              hipStream_t stream)
{
    const float* x   = (const float*)d_in[0];
    const float* Wx1 = (const float*)d_in[1];
    const float* Wh1 = (const float*)d_in[2];
    const float* b1  = (const float*)d_in[3];
    const float* g1  = (const float*)d_in[4];
    const float* be1 = (const float*)d_in[5];
    const float* Wx2 = (const float*)d_in[6];
    const float* Wh2 = (const float*)d_in[7];
    const float* b2  = (const float*)d_in[8];
    const float* g2  = (const float*)d_in[9];
    const float* be2 = (const float*)d_in[10];
    const float* Wd1 = (const float*)d_in[11];
    const float* bd1 = (const float*)d_in[12];
    const float* Wd2 = (const float*)d_in[13];
    const float* bd2 = (const float*)d_in[14];
    float* out = (float*)d_out;

    char* ws = (char*)d_ws;
    __half* xW    = (__half*)(ws);                   // 128 MiB  [B*T, 2048]
    __half* h1    = (__half*)(ws + 134217728);       // 32 MiB   [B*T, 512]
    __half* h2    = (__half*)(ws + 167772160);       // 32 MiB
    float*  accum = (float*) (ws + 201326592);       // 2048 f32
    u32*    cnt   = (u32*)   (ws + 201334784);       // 1024 u32 barrier flags
    float*  s1    = (float*) (ws + 201338880);
    float*  t1    = s1 + HH;
    float*  s2    = t1 + HH;
    float*  t2    = s2 + HH;

    const int M = BB * TT;  // 32768

    zero_init<<<1, 256, 0, stream>>>(accum, cnt);

    gemm_mfma<false, false><<<dim3(16, M / 128), 256, 0, stream>>>(
        x, Wx1, b1, nullptr, nullptr, xW, FF);

    lstm_scan_mfma<<<32, 512, 0, stream>>>(xW, Wh1, h1, cnt, accum);
    bn_finalize<<<1, 512, 0, stream>>>(accum, g1, be1, s1, t1);

    gemm_mfma<true, true><<<dim3(16, M / 128), 256, 0, stream>>>(
        h1, Wx2, b2, s1, t1, xW, HH);

    lstm_scan_mfma<<<32, 512, 0, stream>>>(xW, Wh2, h2, cnt + 512, accum + 1024);
    bn_finalize<<<1, 512, 0, stream>>>(accum + 1024, g2, be2, s2, t2);

    head_kernel<<<M / 16, 256, 0, stream>>>(h2, s2, t2, Wd1, bd1, Wd2, bd2, out);
}